// Round 1
// baseline (888.660 us; speedup 1.0000x reference)
//
#include <hip/hip_runtime.h>

// AddIdentityTLUT: elementwise
//   addr  = x * 2^-shamt
//   large = addr > 0
//   rem   = (x*2) * alpha
//   mixed = large ? addr : rem
//   y     = log2(mixed)
//   out   = large ? y : y + falpha
//
// Memory-bound: 1.074 GB traffic for 128Mi f32 elems -> ~170us at 6.3 TB/s.
// This version: grid-stride (2048 blocks), 4x float4 unroll per thread
// (64 B/lane in flight), nontemporal loads/stores (nt flag, no L2/L3
// allocation for pure streams). Math identical to prior version.

typedef float f32x4 __attribute__((ext_vector_type(4)));

__device__ __forceinline__ float addid_op(float xv, float scale, float alpha, float falpha)
{
    float addr  = xv * scale;
    bool  large = addr > 0.0f;
    float mixed = large ? addr : (xv * 2.0f) * alpha;
    float y     = __log2f(mixed);
    return large ? y : y + falpha;
}

__device__ __forceinline__ f32x4 addid_op4(f32x4 v, float scale, float alpha, float falpha)
{
    f32x4 r;
    r.x = addid_op(v.x, scale, alpha, falpha);
    r.y = addid_op(v.y, scale, alpha, falpha);
    r.z = addid_op(v.z, scale, alpha, falpha);
    r.w = addid_op(v.w, scale, alpha, falpha);
    return r;
}

__global__ __launch_bounds__(256) void addid_tlut_kernel(
    const float* __restrict__ x,
    float* __restrict__ out,
    const float* __restrict__ alpha_p,
    const float* __restrict__ falpha_p,
    const int* __restrict__ shamt_p,
    long long n)
{
    const float alpha  = *alpha_p;
    const float falpha = *falpha_p;
    const int   shamt  = *shamt_p;
    const float scale  = exp2f((float)(-shamt));   // 2^-shamt

    const long long n4  = n >> 2;                  // full float4 chunks
    const long long nth = (long long)gridDim.x * blockDim.x;
    const long long tid = (long long)blockIdx.x * blockDim.x + threadIdx.x;

    const f32x4* __restrict__ xv = reinterpret_cast<const f32x4*>(x);
    f32x4* __restrict__ ov       = reinterpret_cast<f32x4*>(out);

    long long i = tid;

    // Main loop: 4 independent float4 streams in flight per thread.
    for (; i + 3 * nth < n4; i += 4 * nth) {
        f32x4 v0 = __builtin_nontemporal_load(xv + i);
        f32x4 v1 = __builtin_nontemporal_load(xv + i + nth);
        f32x4 v2 = __builtin_nontemporal_load(xv + i + 2 * nth);
        f32x4 v3 = __builtin_nontemporal_load(xv + i + 3 * nth);

        f32x4 r0 = addid_op4(v0, scale, alpha, falpha);
        f32x4 r1 = addid_op4(v1, scale, alpha, falpha);
        f32x4 r2 = addid_op4(v2, scale, alpha, falpha);
        f32x4 r3 = addid_op4(v3, scale, alpha, falpha);

        __builtin_nontemporal_store(r0, ov + i);
        __builtin_nontemporal_store(r1, ov + i + nth);
        __builtin_nontemporal_store(r2, ov + i + 2 * nth);
        __builtin_nontemporal_store(r3, ov + i + 3 * nth);
    }

    // Remainder float4s.
    for (; i < n4; i += nth) {
        f32x4 v = __builtin_nontemporal_load(xv + i);
        __builtin_nontemporal_store(addid_op4(v, scale, alpha, falpha), ov + i);
    }

    // Scalar tail (n % 4 elements), single thread — absent for 128Mi.
    if (tid == 0) {
        for (long long j = (n4 << 2); j < n; ++j)
            out[j] = addid_op(x[j], scale, alpha, falpha);
    }
}

extern "C" void kernel_launch(void* const* d_in, const int* in_sizes, int n_in,
                              void* d_out, int out_size, void* d_ws, size_t ws_size,
                              hipStream_t stream)
{
    const float* x        = (const float*)d_in[0];
    const float* alpha_p  = (const float*)d_in[1];
    const float* falpha_p = (const float*)d_in[2];
    const int*   shamt_p  = (const int*)d_in[3];
    float* out = (float*)d_out;

    long long n  = (long long)in_sizes[0];
    long long n4 = n >> 2;
    const int block = 256;

    long long want = (n4 + block - 1) / block;
    if (want < 1) want = 1;
    unsigned grid = (unsigned)((want < 2048) ? want : 2048);  // 8 blocks/CU, grid-stride

    addid_tlut_kernel<<<dim3(grid), dim3(block), 0, stream>>>(
        x, out, alpha_p, falpha_p, shamt_p, n);
}

// Round 4
// 851.763 us; speedup vs baseline: 1.0433x; 1.0433x over previous
//
#include <hip/hip_runtime.h>

// AddIdentityTLUT: elementwise
//   addr  = x * 2^-shamt
//   large = addr > 0
//   rem   = (x*2) * alpha
//   mixed = large ? addr : rem
//   y     = log2(mixed)
//   out   = large ? y : y + falpha
//
// Memory-bound: 1.074 GB traffic for 128Mi f32 elems -> ~170us at 6.3 TB/s.
// R1 post-mortem: nontemporal + 4-distant-stream bundle cost ~74us at the
// kernel level (nt bypasses the L2 aggregation the fills rely on). R2:
// regular cached float4 loads/stores, ONE lane-contiguous stream,
// grid-stride over 2048 blocks (32 waves/CU). Math unchanged.
// (R2/R3 benches were infra failures — resubmitting unchanged.)

typedef float f32x4 __attribute__((ext_vector_type(4)));

__device__ __forceinline__ float addid_op(float xv, float scale, float alpha, float falpha)
{
    float addr  = xv * scale;
    bool  large = addr > 0.0f;
    float mixed = large ? addr : (xv * 2.0f) * alpha;
    float y     = __log2f(mixed);
    return large ? y : y + falpha;
}

__device__ __forceinline__ f32x4 addid_op4(f32x4 v, float scale, float alpha, float falpha)
{
    f32x4 r;
    r.x = addid_op(v.x, scale, alpha, falpha);
    r.y = addid_op(v.y, scale, alpha, falpha);
    r.z = addid_op(v.z, scale, alpha, falpha);
    r.w = addid_op(v.w, scale, alpha, falpha);
    return r;
}

__global__ __launch_bounds__(256) void addid_tlut_kernel(
    const float* __restrict__ x,
    float* __restrict__ out,
    const float* __restrict__ alpha_p,
    const float* __restrict__ falpha_p,
    const int* __restrict__ shamt_p,
    long long n)
{
    const float alpha  = *alpha_p;
    const float falpha = *falpha_p;
    const int   shamt  = *shamt_p;
    const float scale  = exp2f((float)(-shamt));   // 2^-shamt

    const long long n4  = n >> 2;                  // full float4 chunks
    const long long nth = (long long)gridDim.x * blockDim.x;
    const long long tid = (long long)blockIdx.x * blockDim.x + threadIdx.x;

    const f32x4* __restrict__ xv = reinterpret_cast<const f32x4*>(x);
    f32x4* __restrict__ ov       = reinterpret_cast<f32x4*>(out);

    // One lane-contiguous float4 stream; regular cached loads/stores.
    for (long long i = tid; i < n4; i += nth) {
        f32x4 v = xv[i];
        ov[i] = addid_op4(v, scale, alpha, falpha);
    }

    // Scalar tail (n % 4 elements) — absent for 128Mi input.
    if (tid == 0) {
        for (long long j = (n4 << 2); j < n; ++j)
            out[j] = addid_op(x[j], scale, alpha, falpha);
    }
}

extern "C" void kernel_launch(void* const* d_in, const int* in_sizes, int n_in,
                              void* d_out, int out_size, void* d_ws, size_t ws_size,
                              hipStream_t stream)
{
    const float* x        = (const float*)d_in[0];
    const float* alpha_p  = (const float*)d_in[1];
    const float* falpha_p = (const float*)d_in[2];
    const int*   shamt_p  = (const int*)d_in[3];
    float* out = (float*)d_out;

    long long n  = (long long)in_sizes[0];
    long long n4 = (n + 3) >> 2;
    const int block = 256;

    long long want = (n4 + block - 1) / block;
    if (want < 1) want = 1;
    unsigned grid = (unsigned)((want < 2048) ? want : 2048);  // 8 blocks/CU, grid-stride

    addid_tlut_kernel<<<dim3(grid), dim3(block), 0, stream>>>(
        x, out, alpha_p, falpha_p, shamt_p, n);
}

// Round 5
// 811.854 us; speedup vs baseline: 1.0946x; 1.0492x over previous
//
#include <hip/hip_runtime.h>

// AddIdentityTLUT: elementwise
//   addr  = x * 2^-shamt
//   large = addr > 0
//   rem   = (x*2) * alpha
//   mixed = large ? addr : rem          (== addr*is_large + rem*is_small)
//   y     = log2(mixed)
//   out   = large ? y : y + falpha      (== y + falpha*is_small)
//
// Memory-bound: 1.074 GB traffic for 128Mi f32 elems -> ~169us at 6.35 TB/s.
// Session ladder (constant ~680us harness fill floor in every trace):
//   R0 exact-grid 1xfloat4/thread cached       = 815.1us  <- best (x2 sessions)
//   R1 grid-stride + nontemporal + 4 streams   = 888.7us  (nt/streams ~ -37us)
//   R4 grid-stride cached contiguous           = 851.8us  (grid-stride ~ -37us)
// Lesson: for this pure-stream op, exact-grid one-shot threads beat a
// grid-stride loop (no loop-carried vmcnt serialization, no bound-check
// overhead, fire-and-forget stores). Reverting to R0 structure.

__global__ __launch_bounds__(256) void addid_tlut_kernel(
    const float* __restrict__ x,
    float* __restrict__ out,
    const float* __restrict__ alpha_p,
    const float* __restrict__ falpha_p,
    const int* __restrict__ shamt_p,
    long long n)
{
    const float alpha  = *alpha_p;
    const float falpha = *falpha_p;
    const int   shamt  = *shamt_p;
    const float scale  = exp2f((float)(-shamt));   // 2^-shamt

    long long i4   = (long long)blockIdx.x * blockDim.x + threadIdx.x;
    long long base = i4 * 4;
    if (base >= n) return;

    if (base + 3 < n) {
        // vector path
        float4 v = *reinterpret_cast<const float4*>(x + base);
        float4 r;
        {
            float xv = v.x;
            float addr = xv * scale;
            bool large = addr > 0.0f;
            float mixed = large ? addr : (xv * 2.0f) * alpha;
            float y = __log2f(mixed);
            r.x = large ? y : y + falpha;
        }
        {
            float xv = v.y;
            float addr = xv * scale;
            bool large = addr > 0.0f;
            float mixed = large ? addr : (xv * 2.0f) * alpha;
            float y = __log2f(mixed);
            r.y = large ? y : y + falpha;
        }
        {
            float xv = v.z;
            float addr = xv * scale;
            bool large = addr > 0.0f;
            float mixed = large ? addr : (xv * 2.0f) * alpha;
            float y = __log2f(mixed);
            r.z = large ? y : y + falpha;
        }
        {
            float xv = v.w;
            float addr = xv * scale;
            bool large = addr > 0.0f;
            float mixed = large ? addr : (xv * 2.0f) * alpha;
            float y = __log2f(mixed);
            r.w = large ? y : y + falpha;
        }
        *reinterpret_cast<float4*>(out + base) = r;
    } else {
        // scalar tail
        for (long long j = base; j < n; ++j) {
            float xv = x[j];
            float addr = xv * scale;
            bool large = addr > 0.0f;
            float mixed = large ? addr : (xv * 2.0f) * alpha;
            float y = __log2f(mixed);
            out[j] = large ? y : y + falpha;
        }
    }
}

extern "C" void kernel_launch(void* const* d_in, const int* in_sizes, int n_in,
                              void* d_out, int out_size, void* d_ws, size_t ws_size,
                              hipStream_t stream) {
    const float* x        = (const float*)d_in[0];
    const float* alpha_p  = (const float*)d_in[1];
    const float* falpha_p = (const float*)d_in[2];
    const int*   shamt_p  = (const int*)d_in[3];
    float* out = (float*)d_out;

    long long n = (long long)in_sizes[0];
    long long n4 = (n + 3) / 4;                 // one thread per float4
    int block = 256;
    long long grid = (n4 + block - 1) / block;

    addid_tlut_kernel<<<(dim3)(unsigned)grid, block, 0, stream>>>(
        x, out, alpha_p, falpha_p, shamt_p, n);
}